// Round 17
// baseline (294.350 us; speedup 1.0000x reference)
//
#include <hip/hip_runtime.h>
#include <hip/hip_bf16.h>

typedef short bf16x8 __attribute__((ext_vector_type(8)));
typedef float f32x4  __attribute__((ext_vector_type(4)));

constexpr int HW = 4096;   // 64*64 pixels
constexpr int CT = 31;     // time channels
constexpr int CP = 128;    // poi channels
constexpr int CO = 64;     // output channels

__device__ __forceinline__ short f2bf(float x) {
    __hip_bfloat16 h = __float2bfloat16(x);
    return *reinterpret_cast<short*>(&h);
}

// High-TLP variant: __launch_bounds__(256,8) caps VGPR at 64 -> 8 waves/SIMD
// (32/CU). Wave owns ONE o-subtile (wcf[4]=16 VGPRs) x 32-px strip; the 4
// waves of a block share the strip (poi x4 via L1) and split o. Latency is
// hidden by wave count, not by register prefetch (r11-r16 showed compiler
// never sustains >~2 in-flight loads/wave; at 32 waves/CU that's enough).
// Stores: per o-row, wave writes 128 B aligned-contiguous (2 x 64 B tiles).
// grid = 32 images * 128 strips = 4096 blocks of 256 threads.
__global__ __launch_bounds__(256, 8)
void poi_mfma6(const float* __restrict__ poi,
               const float* __restrict__ tin,
               const float* __restrict__ wm,
               const float* __restrict__ bm,
               const float* __restrict__ wf,
               const float* __restrict__ bf,
               const float* __restrict__ wc,
               const float* __restrict__ bc,
               float* __restrict__ out)
{
    const int lane = threadIdx.x & 63;
    const int m    = lane & 15;       // free index: o (B,D-col) / px (A-row)
    const int g    = lane >> 4;       // 4-lane group: k-subrange / D row-group
    const int wid  = threadIdx.x >> 6;                      // o-subtile id 0..3
    const int b    = blockIdx.x >> 7;                       // 128 strips per image
    const int px0  = (blockIdx.x & 127) << 5;               // 32-px strip base

    // ---------- one-time weight fragments: ONE o-subtile = 16 VGPRs ----------
    bf16x8 wcf[4];                    // [k-frag], B operand
    #pragma unroll
    for (int kf = 0; kf < 4; ++kf)
      #pragma unroll
      for (int j = 0; j < 8; ++j)
        wcf[kf][j] = f2bf(wc[(wid * 16 + m) * CP + kf * 32 + g * 8 + j]);

    bf16x8 wmf[2];                    // wm: 32x31 padded to 32x32 (A operand)
    #pragma unroll
    for (int t2 = 0; t2 < 2; ++t2)
      #pragma unroll
      for (int j = 0; j < 8; ++j) {
        const int c = g * 8 + j;
        wmf[t2][j] = (c < CT) ? f2bf(wm[(t2 * 16 + m) * CT + c]) : (short)0;
      }
    float wff[8]; f32x4 bmf[2];
    #pragma unroll
    for (int t2 = 0; t2 < 2; ++t2)
      #pragma unroll
      for (int r = 0; r < 4; ++r) {
        wff[t2 * 4 + r] = wf[t2 * 16 + g * 4 + r];
        bmf[t2][r]      = bm[t2 * 16 + g * 4 + r];
      }
    const float bcf = bc[wid * 16 + m];
    const float bfv = bf[0];

    const float* tbase = tin + (size_t)b * CT * HW;
    const float* pbase = poi + (size_t)b * CP * HW;
    float*       obase = out + (size_t)b * CO * HW;

    #pragma unroll
    for (int t = 0; t < 2; ++t) {
        const int pxt = px0 + t * 16;
        const float* tb = tbase + pxt + m;
        const float* pb = pbase + pxt + m;

        // ---- stage 1: tval = relu(wf . relu(wm@time + bm) + bf) ----
        bf16x8 tf;
        #pragma unroll
        for (int j = 0; j < 8; ++j) {
            const int c = g * 8 + j;
            tf[j] = (c < CT) ? f2bf(tb[(size_t)c * HW]) : (short)0;
        }
        f32x4 z0 = __builtin_amdgcn_mfma_f32_16x16x32_bf16(wmf[0], tf, bmf[0], 0, 0, 0);
        f32x4 z1 = __builtin_amdgcn_mfma_f32_16x16x32_bf16(wmf[1], tf, bmf[1], 0, 0, 0);
        float s1 = 0.f;
        #pragma unroll
        for (int r = 0; r < 4; ++r) {
            s1 = fmaf(fmaxf(z0[r], 0.f), wff[r],     s1);
            s1 = fmaf(fmaxf(z1[r], 0.f), wff[4 + r], s1);
        }
        s1 += __shfl_xor(s1, 16, 64);         // sum hidden across lane-groups
        s1 += __shfl_xor(s1, 32, 64);
        const float tval = fmaxf(s1 + bfv, 0.f);   // valid for px = pxt + m
        f32x4 tv;                                  // transpose to D-row layout
        #pragma unroll
        for (int r = 0; r < 4; ++r) tv[r] = __shfl(tval, g * 4 + r, 64);

        // ---- stage 2: A = poi (M=px), B = wc (N=o), K=128 in 4 MFMAs ----
        bf16x8 pfv[4];
        #pragma unroll
        for (int kf = 0; kf < 4; ++kf)
          #pragma unroll
          for (int j = 0; j < 8; ++j)
            pfv[kf][j] = f2bf(pb[(size_t)(kf * 32 + g * 8 + j) * HW]);

        f32x4 a = {0.f, 0.f, 0.f, 0.f};
        #pragma unroll
        for (int kf = 0; kf < 4; ++kf)
            a = __builtin_amdgcn_mfma_f32_16x16x32_bf16(pfv[kf], wcf[kf], a, 0, 0, 0);

        f32x4 v;
        #pragma unroll
        for (int r = 0; r < 4; ++r) v[r] = fmaf(tv[r], a[r], bcf);
        __builtin_nontemporal_store(
            v, reinterpret_cast<f32x4*>(
                   obase + pxt + g * 4 + (size_t)(wid * 16 + m) * HW));
    }
}

extern "C" void kernel_launch(void* const* d_in, const int* in_sizes, int n_in,
                              void* d_out, int out_size, void* d_ws, size_t ws_size,
                              hipStream_t stream) {
    const float* poi = (const float*)d_in[0];
    const float* tin = (const float*)d_in[1];
    const float* wm  = (const float*)d_in[2];
    const float* bm  = (const float*)d_in[3];
    const float* wf  = (const float*)d_in[4];
    const float* bf  = (const float*)d_in[5];
    const float* wc  = (const float*)d_in[6];
    const float* bc  = (const float*)d_in[7];
    float* out = (float*)d_out;

    // 32 images x 128 strips (32 px each); block = 4 o-split waves
    hipLaunchKernelGGL(poi_mfma6, dim3(4096), dim3(256), 0, stream,
                       poi, tin, wm, bm, wf, bf, wc, bc, out);
}

// Round 18
// 59.050 us; speedup vs baseline: 4.9848x; 4.9848x over previous
//
#include <hip/hip_runtime.h>
#include <hip/hip_bf16.h>

typedef short bf16x8 __attribute__((ext_vector_type(8)));
typedef float f32x4  __attribute__((ext_vector_type(4)));

constexpr int HW = 4096;   // 64*64 pixels
constexpr int CT = 31;     // time channels
constexpr int CZ = 32;     // hidden channels
constexpr int CP = 128;    // poi channels
constexpr int CO = 64;     // output channels

__device__ __forceinline__ short f2bf(float x) {
    __hip_bfloat16 h = __float2bfloat16(x);
    return *reinterpret_cast<short*>(&h);
}

// ---------------- kernel 1: per-pixel time MLP -> t[b*HW+px] (round-2 proven) ----------------
__global__ __launch_bounds__(256)
void time_mlp(const float* __restrict__ tin,
              const float* __restrict__ wm,
              const float* __restrict__ bm,
              const float* __restrict__ wf,
              const float* __restrict__ bf,
              float* __restrict__ tbuf)
{
    const int gid = blockIdx.x * 256 + threadIdx.x;           // 131072 threads
    const float* tp = tin + (size_t)(gid >> 12) * CT * HW + (gid & (HW - 1));

    float tr[CT];
    #pragma unroll
    for (int c = 0; c < CT; ++c) tr[c] = tp[(size_t)c * HW];  // 31 indep coalesced

    float acc = bf[0];
    #pragma unroll
    for (int k = 0; k < CZ; ++k) {
        float z = bm[k];                                      // uniform s_load
        #pragma unroll
        for (int c = 0; c < CT; ++c)
            z = fmaf(wm[k * CT + c], tr[c], z);               // uniform s_load
        acc = fmaf(wf[k], fmaxf(z, 0.f), acc);
    }
    tbuf[gid] = fmaxf(acc, 0.f);
}

// ---------------- kernel 2: slim MFMA GEMM, 8 waves/SIMD ----------------
// Wave = ONE o-subtile (16 o's, wcf[4]=16 regs) x 32-px strip; block's 4 waves
// share the strip (poi x4 via L1) and split o. ~52 live regs -> fits the
// 64-reg / 8-wave-per-SIMD budget WITHOUT spill (r17 spilled because stage-1
// state pushed it past 64; stage 1 now lives in kernel 1).
// Latency hidden by TLP: 32 waves/CU x ~2 loads in flight = 16 KB/CU.
// Stores: r9-verified contiguous 64 B float4 per lane, nontemporal.
__global__ __launch_bounds__(256, 8)
void poi_gemm_mfma(const float* __restrict__ poi,
                   const float* __restrict__ tbuf,
                   const float* __restrict__ wc,
                   const float* __restrict__ bc,
                   float* __restrict__ out)
{
    const int lane = threadIdx.x & 63;
    const int m    = lane & 15;       // free index: o (B,D-col) / px (A-row)
    const int g    = lane >> 4;       // 4-lane group: k-subrange / D row-group
    const int wid  = threadIdx.x >> 6;                      // o-subtile id 0..3
    const int b    = blockIdx.x >> 7;                       // 128 strips per image
    const int px0  = (blockIdx.x & 127) << 5;               // 32-px strip base

    // one-time weight fragment: ONE o-subtile = 16 VGPRs (layout verified r8/r9)
    bf16x8 wcf[4];                    // [k-frag], B operand
    #pragma unroll
    for (int kf = 0; kf < 4; ++kf)
      #pragma unroll
      for (int j = 0; j < 8; ++j)
        wcf[kf][j] = f2bf(wc[(wid * 16 + m) * CP + kf * 32 + g * 8 + j]);
    const float bcf = bc[wid * 16 + m];

    const float* pbase = poi  + (size_t)b * CP * HW;
    const float* tb    = tbuf + (size_t)b * HW;
    float*       obase = out  + (size_t)b * CO * HW;

    #pragma unroll 1                  // keep one tile's regs live at a time
    for (int t = 0; t < 2; ++t) {
        const int pxt = px0 + t * 16;
        const float* pb = pbase + pxt + m;

        // A fragment: poi (M=px), 32 coalesced scalar loads + cvt
        bf16x8 pfv[4];
        #pragma unroll
        for (int kf = 0; kf < 4; ++kf)
          #pragma unroll
          for (int j = 0; j < 8; ++j)
            pfv[kf][j] = f2bf(pb[(size_t)(kf * 32 + g * 8 + j) * HW]);

        f32x4 a = {0.f, 0.f, 0.f, 0.f};
        #pragma unroll
        for (int kf = 0; kf < 4; ++kf)
            a = __builtin_amdgcn_mfma_f32_16x16x32_bf16(pfv[kf], wcf[kf], a, 0, 0, 0);

        // t for this lane's 4 px: broadcast float4 (same for all m at fixed g)
        const f32x4 tv = *reinterpret_cast<const f32x4*>(tb + pxt + g * 4);

        f32x4 v;
        #pragma unroll
        for (int r = 0; r < 4; ++r) v[r] = fmaf(tv[r], a[r], bcf);
        __builtin_nontemporal_store(
            v, reinterpret_cast<f32x4*>(
                   obase + pxt + g * 4 + (size_t)(wid * 16 + m) * HW));
    }
}

extern "C" void kernel_launch(void* const* d_in, const int* in_sizes, int n_in,
                              void* d_out, int out_size, void* d_ws, size_t ws_size,
                              hipStream_t stream) {
    const float* poi = (const float*)d_in[0];
    const float* tin = (const float*)d_in[1];
    const float* wm  = (const float*)d_in[2];
    const float* bm  = (const float*)d_in[3];
    const float* wf  = (const float*)d_in[4];
    const float* bf  = (const float*)d_in[5];
    const float* wc  = (const float*)d_in[6];
    const float* bc  = (const float*)d_in[7];
    float* out  = (float*)d_out;
    float* tbuf = (float*)d_ws;                 // 131072 floats = 512 KiB

    hipLaunchKernelGGL(time_mlp, dim3(512), dim3(256), 0, stream,
                       tin, wm, bm, wf, bf, tbuf);
    // 32 images x 128 strips (32 px); block = 4 o-split waves
    hipLaunchKernelGGL(poi_gemm_mfma, dim3(4096), dim3(256), 0, stream,
                       poi, tbuf, wc, bc, out);
}

// Round 19
// 44.525 us; speedup vs baseline: 6.6108x; 1.3262x over previous
//
#include <hip/hip_runtime.h>
#include <hip/hip_bf16.h>

typedef short bf16x8 __attribute__((ext_vector_type(8)));
typedef float f32x4  __attribute__((ext_vector_type(4)));
typedef unsigned int u32;
typedef unsigned int u32x4 __attribute__((ext_vector_type(4)));

constexpr int HW = 4096;   // 64*64 pixels
constexpr int CT = 31;     // time channels
constexpr int CZ = 32;     // hidden channels
constexpr int CP = 128;    // poi channels
constexpr int CO = 64;     // output channels

__device__ __forceinline__ u32 f2bfu(float x) {
    __hip_bfloat16 h = __float2bfloat16(x);
    return (u32)*reinterpret_cast<unsigned short*>(&h);
}

// ---------------- kernel 1: time MLP, 2 px/thread via float2 ----------------
// 256 blocks x 256 thr = 65536 threads x 2 px. 31 independent float2 loads
// hoisted ahead of the 2000-cycle FMA chain (sched_barrier pins them).
__global__ __launch_bounds__(256)
void time_mlp2(const float* __restrict__ tin,
               const float* __restrict__ wm,
               const float* __restrict__ bm,
               const float* __restrict__ wf,
               const float* __restrict__ bf,
               float* __restrict__ tbuf)
{
    const int gid = blockIdx.x * 256 + threadIdx.x;
    const int px  = gid * 2;                 // global pixel pair (even)
    const int b   = px >> 12;
    const float* tp = tin + (size_t)b * CT * HW + (px & (HW - 1));

    float2 tr[CT];
    #pragma unroll
    for (int c = 0; c < CT; ++c)
        tr[c] = *reinterpret_cast<const float2*>(tp + (size_t)c * HW);
    __builtin_amdgcn_sched_barrier(0);

    float ax = bf[0], ay = ax;
    #pragma unroll
    for (int k = 0; k < CZ; ++k) {
        float zx = bm[k], zy = zx;           // uniform s_load
        #pragma unroll
        for (int c = 0; c < CT; ++c) {
            const float w = wm[k * CT + c];  // uniform s_load
            zx = fmaf(w, tr[c].x, zx);
            zy = fmaf(w, tr[c].y, zy);
        }
        const float wk = wf[k];
        ax = fmaf(wk, fmaxf(zx, 0.f), ax);
        ay = fmaf(wk, fmaxf(zy, 0.f), ay);
    }
    float2 r; r.x = fmaxf(ax, 0.f); r.y = fmaxf(ay, 0.f);
    *reinterpret_cast<float2*>(tbuf + px) = r;
}

// ---------------- kernel 2: MFMA GEMM with T14 LDS staging ----------------
// Block = 64-px strip. Stage: 16 indep float2 loads/thread -> bulk vmcnt ->
// cvt bf16 + 4 ds_write_b128 into [px][ch] LDS tile, XOR-swizzled
// (dword ^= ((px>>1)&7)<<2; write & read both bank-uniform). One barrier.
// Compute: wave = one o-subtile x 4 px-tiles; per tile 4 ds_read_b128 +
// 4 MFMA + float4 tval + nt float4 store (r9/r18-verified layout).
// grid = 32 images * 64 strips = 2048 blocks of 256 threads.
__global__ __launch_bounds__(256)
void poi_gemm_lds(const float* __restrict__ poi,
                  const float* __restrict__ tbuf,
                  const float* __restrict__ wc,
                  const float* __restrict__ bc,
                  float* __restrict__ out)
{
    __shared__ __align__(16) unsigned short s_poi[64 * CP];   // bf16 [px][ch], 16 KiB

    const int tid  = threadIdx.x;
    const int lane = tid & 63;
    const int m    = lane & 15;      // o within subtile (B/D col)
    const int g    = lane >> 4;      // 4-lane group (k-subrange / D row-group)
    const int wid  = tid >> 6;       // o-subtile id 0..3
    const int b    = blockIdx.x >> 6;            // 64 strips per image
    const int px0  = (blockIdx.x & 63) << 6;     // 64-px strip base

    // one-time weight fragment: ONE o-subtile = 16 VGPRs (layout verified r8+)
    bf16x8 wcf[4];
    #pragma unroll
    for (int kf = 0; kf < 4; ++kf)
      #pragma unroll
      for (int j = 0; j < 8; ++j)
        wcf[kf][j] = (short)f2bfu(wc[(wid * 16 + m) * CP + kf * 32 + g * 8 + j]);
    const float bcf = bc[wid * 16 + m];

    // ---- stage: poi[128ch][64px] f32 -> LDS bf16 [px][ch], swizzled ----
    {
        const int p2 = tid & 31;             // px pair: rows 2*p2, 2*p2+1
        const int cg = tid >> 5;             // ch group: ch = cg*16 + j
        const float* src = poi + (size_t)b * CP * HW + (size_t)(cg * 16) * HW
                               + px0 + p2 * 2;
        float2 v[16];
        #pragma unroll
        for (int j = 0; j < 16; ++j)
            v[j] = *reinterpret_cast<const float2*>(src + (size_t)j * HW);
        __builtin_amdgcn_sched_barrier(0);   // all 16 loads issued before use

        u32 r0[8], r1[8];                    // packed bf16 pairs (even|odd ch)
        #pragma unroll
        for (int j = 0; j < 8; ++j) {
            r0[j] = f2bfu(v[2 * j].x) | (f2bfu(v[2 * j + 1].x) << 16);
            r1[j] = f2bfu(v[2 * j].y) | (f2bfu(v[2 * j + 1].y) << 16);
        }
        u32* lds = reinterpret_cast<u32*>(s_poi);
        const int swz = (p2 & 7) << 2;       // ((px>>1)&7)<<2, same for both rows
        const int d0  = (2 * p2) * (CP / 2) + cg * 8;
        const int d1  = d0 + (CP / 2);
        u32x4 a0 = {r0[0], r0[1], r0[2], r0[3]};
        u32x4 a1 = {r0[4], r0[5], r0[6], r0[7]};
        u32x4 b0 = {r1[0], r1[1], r1[2], r1[3]};
        u32x4 b1 = {r1[4], r1[5], r1[6], r1[7]};
        *reinterpret_cast<u32x4*>(lds + ((d0    ) ^ swz)) = a0;
        *reinterpret_cast<u32x4*>(lds + ((d0 + 4) ^ swz)) = a1;
        *reinterpret_cast<u32x4*>(lds + ((d1    ) ^ swz)) = b0;
        *reinterpret_cast<u32x4*>(lds + ((d1 + 4) ^ swz)) = b1;
    }
    __syncthreads();

    // ---- compute: 4 px-tiles, A from LDS, B = wcf, D col=o row=px ----
    const float* tb = tbuf + (size_t)b * HW + px0;
    float* obase = out + (size_t)b * CO * HW + (size_t)(wid * 16 + m) * HW
                       + px0 + g * 4;
    const u32* lds = reinterpret_cast<const u32*>(s_poi);

    #pragma unroll
    for (int t = 0; t < 4; ++t) {
        const int p     = t * 16 + m;
        const int swzr  = ((p >> 1) & 7) << 2;
        const int dbase = p * (CP / 2);

        bf16x8 pfv[4];
        #pragma unroll
        for (int kf = 0; kf < 4; ++kf)
            pfv[kf] = *reinterpret_cast<const bf16x8*>(
                lds + ((dbase + kf * 16 + g * 4) ^ swzr));   // ds_read_b128

        f32x4 a = {0.f, 0.f, 0.f, 0.f};
        #pragma unroll
        for (int kf = 0; kf < 4; ++kf)
            a = __builtin_amdgcn_mfma_f32_16x16x32_bf16(pfv[kf], wcf[kf], a, 0, 0, 0);

        const f32x4 tv = *reinterpret_cast<const f32x4*>(tb + t * 16 + g * 4);
        f32x4 v;
        #pragma unroll
        for (int r = 0; r < 4; ++r) v[r] = fmaf(tv[r], a[r], bcf);
        __builtin_nontemporal_store(v, reinterpret_cast<f32x4*>(obase + t * 16));
    }
}

extern "C" void kernel_launch(void* const* d_in, const int* in_sizes, int n_in,
                              void* d_out, int out_size, void* d_ws, size_t ws_size,
                              hipStream_t stream) {
    const float* poi = (const float*)d_in[0];
    const float* tin = (const float*)d_in[1];
    const float* wm  = (const float*)d_in[2];
    const float* bm  = (const float*)d_in[3];
    const float* wf  = (const float*)d_in[4];
    const float* bf  = (const float*)d_in[5];
    const float* wc  = (const float*)d_in[6];
    const float* bc  = (const float*)d_in[7];
    float* out  = (float*)d_out;
    float* tbuf = (float*)d_ws;                 // 131072 floats = 512 KiB

    hipLaunchKernelGGL(time_mlp2, dim3(256), dim3(256), 0, stream,
                       tin, wm, bm, wf, bf, tbuf);
    hipLaunchKernelGGL(poi_gemm_lds, dim3(2048), dim3(256), 0, stream,
                       poi, tbuf, wc, bc, out);
}